// Round 14
// baseline (50.425 us; speedup 1.0000x reference)
//
#include <hip/hip_runtime.h>
#include <math.h>

// F0Resonance — bit-exact replication of XLA's tiled-scan cumsum (r6/r8/r9/r12).
// jnp.cumsum lowers via ReduceWindowRewriter, base B=16: [32768]->[2048,16],
// sequential fp32 inner scans, recursive carry scan (2048->128->8), one fp32
// combine-add per level. phase(j) = fl(A0[j&15] + P1((j>>4)-1)),
// P1(m)=fl(B1[m&15]+P2(..)). contract(off) REQUIRED (r7: hipcc fuses
// mul+add -> f0ang off 1 ulp -> 0.03 rad at n=32768). sin(exact fp32 phase):
// Cody-Waite (kq*C1 exact in fma: kq<=72e3) + hw v_sin_f32 (REVOLUTIONS).
// Validated absmax = 1 bf16 quantum.
//
// r13->r14: r13's only defect was using the GLOBAL block id in the carry
// window index (m = (bid<<7)+... instead of ((bid&15)<<7)+...): row 0 right,
// all other rows garbage -> absmax 2.0. Fixed here. Geometry kept: osc[8],
// 4096 blocks x 256 thr (16 segs/row), thread = half a scan window.
// (r12 unit re-read: FETCH was ~49 KB, not MB -> no scratch ever; VGPR=20
// likely arch-VGPRs with osc[16] in AGPRs; osc[8] should fit arch regs.)
#pragma clang fp contract(off)

constexpr int NSAMP = 32768;
constexpr int NROWS = 256;   // B*E = 4*64
constexpr int NOCT  = 16;
constexpr int SEGS  = 16;    // blocks per row (2048 samples each)
constexpr int TPB   = 256;
constexpr int GRID  = NROWS * SEGS;   // 4096

// hard barrier against cross-statement fusion on the scalar chain
__device__ __forceinline__ float keepf(float x) {
  asm volatile("" : "+v"(x));
  return x;
}

__global__ __launch_bounds__(TPB, 8) void f0res_k1(
    const float* __restrict__ f0_in,
    const float* __restrict__ dec_in,
    const float* __restrict__ fs_in,
    float* __restrict__ out,
    float* __restrict__ segmax)
{
  const int bid = blockIdx.x;
  const int row = bid >> 4;
  const int seg = bid & 15;
  const int t   = threadIdx.x;

  __shared__ float s_tab[NOCT][64];  // [0:16)=A0 [16:32)=B1 [32:48)=B2 [48:56)=B3
  __shared__ float s_w[NOCT];
  __shared__ float s_red[TPB / 64];

  // ---- fp32 scalar chain (reference roundings; contraction pinned off) ----
  const float f0a = fabsf(f0_in[row]);
  const float dcc = dec_in[row];
  const float fsv = fs_in[row];

  const float MIN_F = (float)(20.0 / 11025.0);
  const float RNG_F = (float)(3000.0 / 11025.0 - 20.0 / 11025.0);
  const float c1s   = keepf(f0a * RNG_F);       // fl32 mul
  const float c2s   = keepf(MIN_F + c1s);       // fl32 add (NOT fma)
  const float f0ang = keepf(c2s * (float)M_PI); // fl32 mul

  const float sg    = 1.0f / (1.0f + expf(-dcc));
  const float dvv   = 1.0f / (1.0f + expf(-sg));   // double sigmoid
  const float dvr   = keepf(dvv * 0.9405f);        // (1-0.01)*0.95
  const float decay = keepf(0.01f + dvr);          // fl32 add (NOT fma)
  const float ldv   = logf(decay + 1e-12f);

  // ---- builder: lane k builds octave k's tables + weight ----
  if (t < NOCT) {
    const int k = t;
    float fac = 0.0f;
    for (int j = 0; j <= k; ++j) fac = fac + fsv;   // 16-elem seq cumsum
    const float x = keepf(f0ang * fac);
    float* tab = s_tab[k];
    float a = 0.0f;
#pragma unroll
    for (int i = 0; i < 16; ++i) { a = a + x;  tab[i]      = a; }
    const float T0 = a; a = 0.0f;
#pragma unroll
    for (int i = 0; i < 16; ++i) { a = a + T0; tab[16 + i] = a; }
    const float T1 = a; a = 0.0f;
#pragma unroll
    for (int i = 0; i < 16; ++i) { a = a + T1; tab[32 + i] = a; }
    const float T2 = a; a = 0.0f;
#pragma unroll
    for (int i = 0; i < 8;  ++i) { a = a + T2; tab[48 + i] = a; }
    float lc = 0.0f;
    for (int j = 0; j <= k; ++j) lc = lc + ldv;     // seq cumsum of log_decay
    s_w[k] = expf(lc);
  }
  __syncthreads();

  // Cody-Waite: 2pi = C1 + C2. C1 = 6.28125 (8-bit mantissa); kq <= ~72e3 so
  // kq*C1 exact inside fma; residual arg err ~5e-6 rad.
  const float C1 = 6.28125f;
  const float C2 = (float)(6.283185307179586476925287 - 6.28125);
  const float INV2PI = (float)0.159154943091895335768883;

  // thread t owns samples j = 8u .. 8u+7, u = seg*256+t (half a scan window)
  const int m  = (seg << 7) + (t >> 1) - 1;  // carry window index w-1
  const int a0base = (t & 1) * 2;            // float4 index into A0

  float osc[8];
#pragma unroll
  for (int e = 0; e < 8; ++e) osc[e] = 0.0f;

#pragma unroll 1   // keep register pressure low (no AGPR shuffling)
  for (int k = 0; k < NOCT; ++k) {
    const float* tab = s_tab[k];
    const float4* tab4 = (const float4*)tab;
    const float w = s_w[k];

    // carry P1(m): exact fp32 per the tiled scan (pure adds)
    float carry = 0.0f;
    if (m >= 0) {
      carry = tab[16 + (m & 15)];
      const int m2 = (m >> 4) - 1;
      if (m2 >= 0) {
        float p2 = tab[32 + (m2 & 15)];
        const int m3 = (m2 >> 4) - 1;
        if (m3 >= 0) p2 = p2 + tab[48 + m3];
        carry = carry + p2;
      }
    }

#pragma unroll
    for (int g = 0; g < 2; ++g) {
      const float4 tv4 = tab4[a0base + g];  // A0 slice, 2 addrs -> broadcast
#pragma unroll
      for (int c = 0; c < 4; ++c) {
        const int e = 4 * g + c;
        const float a0 = (c == 0) ? tv4.x : (c == 1) ? tv4.y
                        : (c == 2) ? tv4.z : tv4.w;
        const float p = a0 + carry;                   // exact ref phase bits
        const float kq = rintf(p * INV2PI);
        float r = __builtin_fmaf(-kq, C1, p);         // exact product in fma
        r = __builtin_fmaf(-kq, C2, r);
        const float fr = r * INV2PI;
        float sv;
        asm("v_sin_f32 %0, %1" : "=v"(sv) : "v"(fr)); // sin(fr * 2pi)
        // fma on OUTPUT accumulation only (phase untouched): validated r9.
        osc[e] = __builtin_fmaf(w, sv, osc[e]);
      }
    }
  }

  // ---- block |max| reduction -> plain store (no init, no atomic) ----
  float lmax = 0.0f;
#pragma unroll
  for (int e = 0; e < 8; ++e) lmax = fmaxf(lmax, fabsf(osc[e]));
#pragma unroll
  for (int off = 32; off >= 1; off >>= 1)
    lmax = fmaxf(lmax, __shfl_xor(lmax, off, 64));
  if ((t & 63) == 0) s_red[t >> 6] = lmax;
  __syncthreads();
  if (t == 0) {
    float mx = s_red[0];
#pragma unroll
    for (int i = 1; i < TPB / 64; ++i) mx = fmaxf(mx, s_red[i]);
    segmax[bid] = mx;
  }

  // ---- raw store, block-local PERMUTED layout (lane-contiguous) ----
  // logical f4 l = 2t+q stored at raw slot q*256 + t (1024B/wave runs)
  float4* o4 = (float4*)out + (size_t)bid * 512;
#pragma unroll
  for (int q = 0; q < 2; ++q) {
    float4 v;
    v.x = osc[4 * q + 0];
    v.y = osc[4 * q + 1];
    v.z = osc[4 * q + 2];
    v.w = osc[4 * q + 3];
    o4[q * 256 + t] = v;
  }
}

__global__ __launch_bounds__(TPB, 8) void f0res_k2(
    float* __restrict__ out,
    const float* __restrict__ segmax)
{
  const int bid = blockIdx.x;
  const int t   = threadIdx.x;
  const int row = bid >> 4;

  float mx = 0.0f;
#pragma unroll
  for (int i = 0; i < SEGS; ++i) mx = fmaxf(mx, segmax[row * SEGS + i]);
  const float inv = 1.0f / (mx + 1e-8f);

  float4* base = (float4*)out + (size_t)bid * 512;

  // gather: logical f4 l = q*256+t lives at raw slot (l&1)*256 + (l>>1)
  //                                              = (t&1)*256 + q*128 + (t>>1)
  float4 v[2];
#pragma unroll
  for (int q = 0; q < 2; ++q) {
    const int s = (t & 1) * 256 + q * 128 + (t >> 1);
    v[q] = base[s];
  }
  // __syncthreads emits s_waitcnt vmcnt(0) before s_barrier: all reads of
  // the chunk complete before any write below -> in-place permute is safe.
  __syncthreads();
#pragma unroll
  for (int q = 0; q < 2; ++q) {
    float4 x = v[q];
    x.x *= inv; x.y *= inv; x.z *= inv; x.w *= inv;
    base[q * 256 + t] = x;   // linear, lane-contiguous
  }
}

extern "C" void kernel_launch(void* const* d_in, const int* in_sizes, int n_in,
                              void* d_out, int out_size, void* d_ws, size_t ws_size,
                              hipStream_t stream) {
    const float* f0  = (const float*)d_in[0];  // (4,64,1)
    const float* dcc = (const float*)d_in[1];  // decay_coefficients
    // d_in[2] = phase_offsets: computed-but-unused in the reference
    const float* fsp = (const float*)d_in[3];  // freq_spacing
    float* out = (float*)d_out;                // (4,64,32768) fp32
    float* segmax = (float*)d_ws;              // 4096 floats, fully written/call

    f0res_k1<<<GRID, TPB, 0, stream>>>(f0, dcc, fsp, out, segmax);
    f0res_k2<<<GRID, TPB, 0, stream>>>(out, segmax);
}

// Round 15
// 47.079 us; speedup vs baseline: 1.0711x; 1.0711x over previous
//
#include <hip/hip_runtime.h>
#include <math.h>

// F0Resonance — bit-exact replication of XLA's tiled-scan cumsum (r6/r8/r14).
// jnp.cumsum lowers via ReduceWindowRewriter, base B=16: [32768]->[2048,16],
// sequential fp32 inner scans, recursive carry scan (2048->128->8), one fp32
// combine-add per level. phase(j) = fl(A0[j&15] + P1((j>>4)-1)),
// P1(m)=fl(B1[m&15]+P2(..)). contract(off) REQUIRED (r7: hipcc fuses
// mul+add -> f0ang off 1 ulp -> 0.03 rad at n=32768).
// Validated absmax = 1 bf16 quantum (r6/r8/r9/r12/r14).
//
// r14->r15 perf (K1 = 88% of time, VALU-issue-bound, ~40 cy/wave-eval):
//  (a) 7-op eval chain: Cody-Waite in REVOLUTION space with split
//      1/2pi = I1+I2. kq = rndne(p*I1); fr = fma(p,I1,-kq) (exact product,
//      one rounding <=3e-8 rev); fr = fma(p,I2,fr). Deletes the final
//      radians->revs mul; arg err ~6e-7 rad (tighter than r14's 5e-6).
//      kq off-by-one near half-integers is harmless (periodicity, |fr|<=.51,
//      range hw-validated r8-r14).
//  (b) unroll 2 on the k-loop: amortize carry/table/branch over 16 evals,
//      double the independent chains. Live ~55 regs < 64 cap of (256,8).
#pragma clang fp contract(off)

constexpr int NSAMP = 32768;
constexpr int NROWS = 256;   // B*E = 4*64
constexpr int NOCT  = 16;
constexpr int SEGS  = 16;    // blocks per row (2048 samples each)
constexpr int TPB   = 256;
constexpr int GRID  = NROWS * SEGS;   // 4096

// hard barrier against cross-statement fusion on the scalar chain
__device__ __forceinline__ float keepf(float x) {
  asm volatile("" : "+v"(x));
  return x;
}

__global__ __launch_bounds__(TPB, 8) void f0res_k1(
    const float* __restrict__ f0_in,
    const float* __restrict__ dec_in,
    const float* __restrict__ fs_in,
    float* __restrict__ out,
    float* __restrict__ segmax)
{
  const int bid = blockIdx.x;
  const int row = bid >> 4;
  const int seg = bid & 15;
  const int t   = threadIdx.x;

  __shared__ float s_tab[NOCT][64];  // [0:16)=A0 [16:32)=B1 [32:48)=B2 [48:56)=B3
  __shared__ float s_w[NOCT];
  __shared__ float s_red[TPB / 64];

  // ---- fp32 scalar chain (reference roundings; contraction pinned off) ----
  const float f0a = fabsf(f0_in[row]);
  const float dcc = dec_in[row];
  const float fsv = fs_in[row];

  const float MIN_F = (float)(20.0 / 11025.0);
  const float RNG_F = (float)(3000.0 / 11025.0 - 20.0 / 11025.0);
  const float c1s   = keepf(f0a * RNG_F);       // fl32 mul
  const float c2s   = keepf(MIN_F + c1s);       // fl32 add (NOT fma)
  const float f0ang = keepf(c2s * (float)M_PI); // fl32 mul

  const float sg    = 1.0f / (1.0f + expf(-dcc));
  const float dvv   = 1.0f / (1.0f + expf(-sg));   // double sigmoid
  const float dvr   = keepf(dvv * 0.9405f);        // (1-0.01)*0.95
  const float decay = keepf(0.01f + dvr);          // fl32 add (NOT fma)
  const float ldv   = logf(decay + 1e-12f);

  // ---- builder: lane k builds octave k's tables + weight ----
  if (t < NOCT) {
    const int k = t;
    float fac = 0.0f;
    for (int j = 0; j <= k; ++j) fac = fac + fsv;   // 16-elem seq cumsum
    const float x = keepf(f0ang * fac);
    float* tab = s_tab[k];
    float a = 0.0f;
#pragma unroll
    for (int i = 0; i < 16; ++i) { a = a + x;  tab[i]      = a; }
    const float T0 = a; a = 0.0f;
#pragma unroll
    for (int i = 0; i < 16; ++i) { a = a + T0; tab[16 + i] = a; }
    const float T1 = a; a = 0.0f;
#pragma unroll
    for (int i = 0; i < 16; ++i) { a = a + T1; tab[32 + i] = a; }
    const float T2 = a; a = 0.0f;
#pragma unroll
    for (int i = 0; i < 8;  ++i) { a = a + T2; tab[48 + i] = a; }
    float lc = 0.0f;
    for (int j = 0; j <= k; ++j) lc = lc + ldv;     // seq cumsum of log_decay
    s_w[k] = expf(lc);
  }
  __syncthreads();

  // split 1/(2pi): I1 = fl32(1/2pi), I2 = fl32(1/2pi - I1).
  // fr = fma(p,I1,-kq) + fma(p,I2,.) gives frac(p/2pi) to ~1e-7 rev.
  const double INV2PI_D = 0.15915494309189533577;
  const float I1 = (float)INV2PI_D;
  const float I2 = (float)(INV2PI_D - (double)I1);

  // thread t owns samples j = 8u .. 8u+7, u = seg*256+t (half a scan window)
  const int m  = (seg << 7) + (t >> 1) - 1;  // carry window index w-1
  const int a0base = (t & 1) * 2;            // float4 index into A0

  float osc[8];
#pragma unroll
  for (int e = 0; e < 8; ++e) osc[e] = 0.0f;

#pragma unroll 2   // amortize per-k overhead, keep regs < 64
  for (int k = 0; k < NOCT; ++k) {
    const float* tab = s_tab[k];
    const float w = s_w[k];

    // carry P1(m): exact fp32 per the tiled scan (pure adds)
    float carry = 0.0f;
    if (m >= 0) {
      carry = tab[16 + (m & 15)];
      const int m2 = (m >> 4) - 1;
      if (m2 >= 0) {
        float p2 = tab[32 + (m2 & 15)];
        const int m3 = (m2 >> 4) - 1;
        if (m3 >= 0) p2 = p2 + tab[48 + m3];
        carry = carry + p2;
      }
    }

    // A0 slice into registers (2 x ds_read_b128, 2 addrs -> broadcast)
    float tv[8];
    *(float4*)&tv[0] = ((const float4*)tab)[a0base];
    *(float4*)&tv[4] = ((const float4*)tab)[a0base + 1];

#pragma unroll
    for (int e = 0; e < 8; ++e) {
      const float p  = tv[e] + carry;               // exact ref phase bits
      const float kq = rintf(p * I1);               // nearest rev (mul+rndne)
      float fr = __builtin_fmaf(p, I1, -kq);        // exact prod - kq, 1 rnd
      fr = __builtin_fmaf(p, I2, fr);               // low-bits correction
      float sv;
      asm("v_sin_f32 %0, %1" : "=v"(sv) : "v"(fr)); // sin(fr * 2pi)
      // fma on OUTPUT accumulation only (phase untouched): validated r9.
      osc[e] = __builtin_fmaf(w, sv, osc[e]);
    }
  }

  // ---- block |max| reduction -> plain store (no init, no atomic) ----
  float lmax = 0.0f;
#pragma unroll
  for (int e = 0; e < 8; ++e) lmax = fmaxf(lmax, fabsf(osc[e]));
#pragma unroll
  for (int off = 32; off >= 1; off >>= 1)
    lmax = fmaxf(lmax, __shfl_xor(lmax, off, 64));
  if ((t & 63) == 0) s_red[t >> 6] = lmax;
  __syncthreads();
  if (t == 0) {
    float mx = s_red[0];
#pragma unroll
    for (int i = 1; i < TPB / 64; ++i) mx = fmaxf(mx, s_red[i]);
    segmax[bid] = mx;
  }

  // ---- raw store, block-local PERMUTED layout (lane-contiguous) ----
  // logical f4 l = 2t+q stored at raw slot q*256 + t (1024B/wave runs)
  float4* o4 = (float4*)out + (size_t)bid * 512;
#pragma unroll
  for (int q = 0; q < 2; ++q) {
    float4 v;
    v.x = osc[4 * q + 0];
    v.y = osc[4 * q + 1];
    v.z = osc[4 * q + 2];
    v.w = osc[4 * q + 3];
    o4[q * 256 + t] = v;
  }
}

__global__ __launch_bounds__(TPB, 8) void f0res_k2(
    float* __restrict__ out,
    const float* __restrict__ segmax)
{
  const int bid = blockIdx.x;
  const int t   = threadIdx.x;
  const int row = bid >> 4;

  float mx = 0.0f;
#pragma unroll
  for (int i = 0; i < SEGS; ++i) mx = fmaxf(mx, segmax[row * SEGS + i]);
  const float inv = 1.0f / (mx + 1e-8f);

  float4* base = (float4*)out + (size_t)bid * 512;

  // gather: logical f4 l = q*256+t lives at raw slot (l&1)*256 + (l>>1)
  //                                              = (t&1)*256 + q*128 + (t>>1)
  float4 v[2];
#pragma unroll
  for (int q = 0; q < 2; ++q) {
    const int s = (t & 1) * 256 + q * 128 + (t >> 1);
    v[q] = base[s];
  }
  // __syncthreads emits s_waitcnt vmcnt(0) before s_barrier: all reads of
  // the chunk complete before any write below -> in-place permute is safe.
  __syncthreads();
#pragma unroll
  for (int q = 0; q < 2; ++q) {
    float4 x = v[q];
    x.x *= inv; x.y *= inv; x.z *= inv; x.w *= inv;
    base[q * 256 + t] = x;   // linear, lane-contiguous
  }
}

extern "C" void kernel_launch(void* const* d_in, const int* in_sizes, int n_in,
                              void* d_out, int out_size, void* d_ws, size_t ws_size,
                              hipStream_t stream) {
    const float* f0  = (const float*)d_in[0];  // (4,64,1)
    const float* dcc = (const float*)d_in[1];  // decay_coefficients
    // d_in[2] = phase_offsets: computed-but-unused in the reference
    const float* fsp = (const float*)d_in[3];  // freq_spacing
    float* out = (float*)d_out;                // (4,64,32768) fp32
    float* segmax = (float*)d_ws;              // 4096 floats, fully written/call

    f0res_k1<<<GRID, TPB, 0, stream>>>(f0, dcc, fsp, out, segmax);
    f0res_k2<<<GRID, TPB, 0, stream>>>(out, segmax);
}

// Round 16
// 45.601 us; speedup vs baseline: 1.1058x; 1.0324x over previous
//
#include <hip/hip_runtime.h>
#include <math.h>

// F0Resonance — bit-exact replication of XLA's tiled-scan cumsum (r6/r8/r14/r15).
// jnp.cumsum lowers via ReduceWindowRewriter, base B=16: [32768]->[2048,16],
// sequential fp32 inner scans, recursive carry scan (2048->128->8), one fp32
// combine-add per level. phase(j) = fl(A0[j&15] + P1((j>>4)-1)),
// P1(m)=fl(B1[m&15]+fl(B2[m2&15]+B3[m3])). contract(off) REQUIRED (r7: hipcc
// fuses mul+add -> f0ang off 1 ulp -> 0.03 rad at n=32768).
// Reduction: revolution-space Cody-Waite split 1/2pi = I1+I2 (r15, ~6e-7
// rad arg err) + hw v_sin_f32 (REVOLUTIONS). Validated absmax = 1 bf16 q.
//
// r15->r16 perf (K1 issue-bound, ~18 instr-equiv/eval vs 7 in the chain):
// hoist the per-(thread,k) carry chain (3 VGPR-addressed ds_read_b32 + ~10
// VALU, amortized over 8 evals) into a precomputed LDS table
// carr[16][128] (8 KB), built once per block with the SAME fp32 add order
// (bit-identical). Main-loop per k: 1 ds_read_b32 (carry, broadcast) +
// 2 ds_read_b128 (A0 slice) + s_w read, all at constant k-offsets ->
// folded into offset: immediates, zero index math.
#pragma clang fp contract(off)

constexpr int NSAMP = 32768;
constexpr int NROWS = 256;   // B*E = 4*64
constexpr int NOCT  = 16;
constexpr int SEGS  = 16;    // blocks per row (2048 samples each)
constexpr int TPB   = 256;
constexpr int GRID  = NROWS * SEGS;   // 4096

// hard barrier against cross-statement fusion on the scalar chain
__device__ __forceinline__ float keepf(float x) {
  asm volatile("" : "+v"(x));
  return x;
}

__global__ __launch_bounds__(TPB, 8) void f0res_k1(
    const float* __restrict__ f0_in,
    const float* __restrict__ dec_in,
    const float* __restrict__ fs_in,
    float* __restrict__ out,
    float* __restrict__ segmax)
{
  const int bid = blockIdx.x;
  const int row = bid >> 4;
  const int seg = bid & 15;
  const int t   = threadIdx.x;

  __shared__ float s_tab[NOCT][64];   // [0:16)=A0 [16:32)=B1 [32:48)=B2 [48:56)=B3
  __shared__ float s_w[NOCT];
  __shared__ float s_carr[NOCT][128]; // precomputed P1 carries per (k, lm)
  __shared__ float s_red[TPB / 64];

  // ---- fp32 scalar chain (reference roundings; contraction pinned off) ----
  const float f0a = fabsf(f0_in[row]);
  const float dcc = dec_in[row];
  const float fsv = fs_in[row];

  const float MIN_F = (float)(20.0 / 11025.0);
  const float RNG_F = (float)(3000.0 / 11025.0 - 20.0 / 11025.0);
  const float c1s   = keepf(f0a * RNG_F);       // fl32 mul
  const float c2s   = keepf(MIN_F + c1s);       // fl32 add (NOT fma)
  const float f0ang = keepf(c2s * (float)M_PI); // fl32 mul

  const float sg    = 1.0f / (1.0f + expf(-dcc));
  const float dvv   = 1.0f / (1.0f + expf(-sg));   // double sigmoid
  const float dvr   = keepf(dvv * 0.9405f);        // (1-0.01)*0.95
  const float decay = keepf(0.01f + dvr);          // fl32 add (NOT fma)
  const float ldv   = logf(decay + 1e-12f);

  // ---- builder 1: lane k builds octave k's tables + weight ----
  if (t < NOCT) {
    const int k = t;
    float fac = 0.0f;
    for (int j = 0; j <= k; ++j) fac = fac + fsv;   // 16-elem seq cumsum
    const float x = keepf(f0ang * fac);
    float* tab = s_tab[k];
    float a = 0.0f;
#pragma unroll
    for (int i = 0; i < 16; ++i) { a = a + x;  tab[i]      = a; }
    const float T0 = a; a = 0.0f;
#pragma unroll
    for (int i = 0; i < 16; ++i) { a = a + T0; tab[16 + i] = a; }
    const float T1 = a; a = 0.0f;
#pragma unroll
    for (int i = 0; i < 16; ++i) { a = a + T1; tab[32 + i] = a; }
    const float T2 = a; a = 0.0f;
#pragma unroll
    for (int i = 0; i < 8;  ++i) { a = a + T2; tab[48 + i] = a; }
    float lc = 0.0f;
    for (int j = 0; j <= k; ++j) lc = lc + ldv;     // seq cumsum of log_decay
    s_w[k] = expf(lc);
  }
  __syncthreads();

  // ---- builder 2: precompute carries carr[k][lm] = P1(seg*128+lm-1) ----
  // SAME fp32 add order as the r14/r15 per-thread chain (bit-identical):
  // carry = fl(B1[m&15] + fl(B2[m2&15] + B3[m3]))
#pragma unroll
  for (int i = 0; i < (NOCT * 128) / TPB; ++i) {
    const int idx = t + i * TPB;      // 0..2047
    const int k   = idx >> 7;
    const int lm  = idx & 127;
    const int m   = (seg << 7) + lm - 1;
    const float* tab = s_tab[k];
    float c = 0.0f;
    if (m >= 0) {
      c = tab[16 + (m & 15)];
      const int m2 = (m >> 4) - 1;
      if (m2 >= 0) {
        float p2 = tab[32 + (m2 & 15)];
        const int m3 = (m2 >> 4) - 1;
        if (m3 >= 0) p2 = p2 + tab[48 + m3];
        c = c + p2;
      }
    }
    s_carr[k][lm] = c;
  }
  __syncthreads();

  // split 1/(2pi): I1 = fl32(1/2pi), I2 = fl32(1/2pi - I1).
  const double INV2PI_D = 0.15915494309189533577;
  const float I1 = (float)INV2PI_D;
  const float I2 = (float)(INV2PI_D - (double)I1);

  // thread t owns samples j = 8u .. 8u+7, u = seg*256+t (half a scan window)
  const int lm = t >> 1;              // local carry index
  const int a0base = (t & 1) * 2;     // float4 index into A0

  float osc[8];
#pragma unroll
  for (int e = 0; e < 8; ++e) osc[e] = 0.0f;

#pragma unroll 2   // amortize per-k overhead, keep regs < 64
  for (int k = 0; k < NOCT; ++k) {
    const float carry = s_carr[k][lm];         // 1 b32, broadcast-friendly
    const float w = s_w[k];

    // A0 slice into registers (2 x ds_read_b128, 2 addrs -> broadcast)
    float tv[8];
    *(float4*)&tv[0] = ((const float4*)s_tab[k])[a0base];
    *(float4*)&tv[4] = ((const float4*)s_tab[k])[a0base + 1];

#pragma unroll
    for (int e = 0; e < 8; ++e) {
      const float p  = tv[e] + carry;               // exact ref phase bits
      const float kq = rintf(p * I1);               // nearest rev (mul+rndne)
      float fr = __builtin_fmaf(p, I1, -kq);        // exact prod - kq, 1 rnd
      fr = __builtin_fmaf(p, I2, fr);               // low-bits correction
      float sv;
      asm("v_sin_f32 %0, %1" : "=v"(sv) : "v"(fr)); // sin(fr * 2pi)
      // fma on OUTPUT accumulation only (phase untouched): validated r9.
      osc[e] = __builtin_fmaf(w, sv, osc[e]);
    }
  }

  // ---- block |max| reduction -> plain store (no init, no atomic) ----
  float lmax = 0.0f;
#pragma unroll
  for (int e = 0; e < 8; ++e) lmax = fmaxf(lmax, fabsf(osc[e]));
#pragma unroll
  for (int off = 32; off >= 1; off >>= 1)
    lmax = fmaxf(lmax, __shfl_xor(lmax, off, 64));
  if ((t & 63) == 0) s_red[t >> 6] = lmax;
  __syncthreads();
  if (t == 0) {
    float mx = s_red[0];
#pragma unroll
    for (int i = 1; i < TPB / 64; ++i) mx = fmaxf(mx, s_red[i]);
    segmax[bid] = mx;
  }

  // ---- raw store, block-local PERMUTED layout (lane-contiguous) ----
  // logical f4 l = 2t+q stored at raw slot q*256 + t (1024B/wave runs)
  float4* o4 = (float4*)out + (size_t)bid * 512;
#pragma unroll
  for (int q = 0; q < 2; ++q) {
    float4 v;
    v.x = osc[4 * q + 0];
    v.y = osc[4 * q + 1];
    v.z = osc[4 * q + 2];
    v.w = osc[4 * q + 3];
    o4[q * 256 + t] = v;
  }
}

__global__ __launch_bounds__(TPB, 8) void f0res_k2(
    float* __restrict__ out,
    const float* __restrict__ segmax)
{
  const int bid = blockIdx.x;
  const int t   = threadIdx.x;
  const int row = bid >> 4;

  float mx = 0.0f;
#pragma unroll
  for (int i = 0; i < SEGS; ++i) mx = fmaxf(mx, segmax[row * SEGS + i]);
  const float inv = 1.0f / (mx + 1e-8f);

  float4* base = (float4*)out + (size_t)bid * 512;

  // gather: logical f4 l = q*256+t lives at raw slot (l&1)*256 + (l>>1)
  //                                              = (t&1)*256 + q*128 + (t>>1)
  float4 v[2];
#pragma unroll
  for (int q = 0; q < 2; ++q) {
    const int s = (t & 1) * 256 + q * 128 + (t >> 1);
    v[q] = base[s];
  }
  // __syncthreads emits s_waitcnt vmcnt(0) before s_barrier: all reads of
  // the chunk complete before any write below -> in-place permute is safe.
  __syncthreads();
#pragma unroll
  for (int q = 0; q < 2; ++q) {
    float4 x = v[q];
    x.x *= inv; x.y *= inv; x.z *= inv; x.w *= inv;
    base[q * 256 + t] = x;   // linear, lane-contiguous
  }
}

extern "C" void kernel_launch(void* const* d_in, const int* in_sizes, int n_in,
                              void* d_out, int out_size, void* d_ws, size_t ws_size,
                              hipStream_t stream) {
    const float* f0  = (const float*)d_in[0];  // (4,64,1)
    const float* dcc = (const float*)d_in[1];  // decay_coefficients
    // d_in[2] = phase_offsets: computed-but-unused in the reference
    const float* fsp = (const float*)d_in[3];  // freq_spacing
    float* out = (float*)d_out;                // (4,64,32768) fp32
    float* segmax = (float*)d_ws;              // 4096 floats, fully written/call

    f0res_k1<<<GRID, TPB, 0, stream>>>(f0, dcc, fsp, out, segmax);
    f0res_k2<<<GRID, TPB, 0, stream>>>(out, segmax);
}